// Round 7
// baseline (415.086 us; speedup 1.0000x reference)
//
#include <hip/hip_runtime.h>
#include <hip/hip_bf16.h>
#include <cstdint>
#include <cstddef>

#define DEV static __device__ __forceinline__

typedef __hip_bfloat16 hb;
typedef __bf16 bf16x8 __attribute__((ext_vector_type(8)));
typedef float f32x4 __attribute__((ext_vector_type(4)));
typedef __attribute__((address_space(1))) unsigned int as1_u32;
typedef __attribute__((address_space(3))) unsigned int as3_u32;

constexpr int B_ = 4, T_ = 4096, C_ = 1024, NFFT = 8192, FB = 4097, H_ = 2048;
constexpr int BT_ = B_ * T_;
constexpr float EPS_ = 1e-5f;
constexpr int TRANS_ = 16;
// twiddle table: [0,240) stage L=16; [240,4080) stage L=256; [4080,6128) untangle.
constexpr int TW_S1 = 0;
constexpr int TW_S2 = 240;
constexpr int TW_UNT = 4080;
constexpr int TW_TOTAL = 6128;

DEV void gload16(const void* gsrc, void* ldst) {
  __builtin_amdgcn_global_load_lds((as1_u32*)gsrc, (as3_u32*)ldst, 16, 0, 0);
}

DEV unsigned short bfbits(float f) {
  hb h = __float2bfloat16(f);
  return __builtin_bit_cast(unsigned short, h);
}
DEV float bf2f(unsigned short u) {
  unsigned int x = ((unsigned int)u) << 16;
  return __builtin_bit_cast(float, x);
}

// ---------------------------------------------------------------------------
// K0: twiddle tables (shared by all fftconv blocks; L2-resident).
// ---------------------------------------------------------------------------
__global__ __launch_bounds__(256) void build_tw(float2* __restrict__ tw) {
  const int i = blockIdx.x * 256 + threadIdx.x;
  if (i < 240) {                        // stage L=16: W_256^{pq}
    const int pos = i / 15, q = i % 15 + 1;
    float sn, cs;
    sincospif((float)(pos * q) * (1.0f / 128.0f), &sn, &cs);
    tw[i] = make_float2(cs, sn);
  } else if (i < 4080) {                // stage L=256: W_4096^{pq}
    const int j = i - 240;
    const int pos = j / 15, q = j % 15 + 1;
    float sn, cs;
    sincospif((float)(pos * q) * (1.0f / 2048.0f), &sn, &cs);
    tw[i] = make_float2(cs, sn);
  } else if (i < TW_TOTAL) {            // untangle: e^{-i pi k/4096}
    const int k = i - TW_UNT;
    float sn, cs;
    sincospif((float)k * (1.0f / 4096.0f), &sn, &cs);
    tw[i] = make_float2(cs, sn);
  }
}

// ---------------------------------------------------------------------------
// K1: keff[f] = rfft(kernel,8192)[f] * sigmoid(logits[f]) * mask(f, cutoff)
// ---------------------------------------------------------------------------
__global__ __launch_bounds__(256) void build_keff(const float* __restrict__ kern,
                                                  const float* __restrict__ logits,
                                                  const int* __restrict__ cutp,
                                                  float* __restrict__ keff) {
  const int f = blockIdx.x;      // 0..4096
  const int tid = threadIdx.x;
  float sr = 0.f, si = 0.f;
#pragma unroll
  for (int u = 0; u < 4; u++) {
    const int k = tid + u * 256;
    const float kv = kern[k];
    const int m = (f * k) & (NFFT - 1);      // exact phase mod 8192
    float sn, cs;
    sincospif((float)m * (1.0f / 4096.0f), &sn, &cs);  // e^{-2pi i m/8192}
    sr = fmaf(kv, cs, sr);
    si = fmaf(kv, -sn, si);
  }
#pragma unroll
  for (int o = 32; o > 0; o >>= 1) { sr += __shfl_xor(sr, o); si += __shfl_xor(si, o); }
  __shared__ float redr[4], redi[4];
  if ((tid & 63) == 0) { redr[tid >> 6] = sr; redi[tid >> 6] = si; }
  __syncthreads();
  if (tid == 0) {
    float kr = redr[0] + redr[1] + redr[2] + redr[3];
    float ki = redi[0] + redi[1] + redi[2] + redi[3];
    const float g = 1.0f / (1.0f + expf(-logits[f]));
    int cc = *cutp; if (cc > FB) cc = FB;
    float msk = 1.0f;
    if (cc < FB) {                           // mask active (None-case otherwise)
      int tr = TRANS_ < cc ? TRANS_ : cc;
      if (f >= cc) msk = 0.0f;
      else if (f >= cc - tr) {
        int i = f - (cc - tr);
        int den = (tr > 1) ? (tr - 1) : 1;
        msk = 0.5f * (1.0f + cospif((float)i / (float)den));
      }
    }
    const float gm = g * msk;
    keff[2 * f] = kr * gm;
    keff[2 * f + 1] = ki * gm;
  }
}

// ---------------------------------------------------------------------------
// K2: per-row LayerNorm stats (mean, rstd) over C. One wave per row.
// ---------------------------------------------------------------------------
__global__ __launch_bounds__(256) void ln_stats(const float* __restrict__ x,
                                                float* __restrict__ mu,
                                                float* __restrict__ rs) {
  const int row = blockIdx.x * 4 + (threadIdx.x >> 6);
  const int l = threadIdx.x & 63;
  const float4* p = (const float4*)(x + (size_t)row * C_);
  float s = 0.f, sq = 0.f;
#pragma unroll
  for (int u = 0; u < 4; u++) {
    float4 v = p[l + 64 * u];
    s += v.x + v.y + v.z + v.w;
    sq += v.x * v.x + v.y * v.y + v.z * v.z + v.w * v.w;
  }
#pragma unroll
  for (int o = 32; o > 0; o >>= 1) { s += __shfl_xor(s, o); sq += __shfl_xor(sq, o); }
  if (l == 0) {
    float m = s * (1.0f / C_);
    float var = sq * (1.0f / C_) - m * m;
    mu[row] = m;
    rs[row] = rsqrtf(var + EPS_);
  }
}

// ---------------------------------------------------------------------------
// K3: apply LN, transpose [B,T,C] -> bf16 [B,C,T], emit per-tile column sums
// (pooled partials from the f32 values, so g_ctx precision is unchanged).
// ---------------------------------------------------------------------------
__global__ __launch_bounds__(256) void ln_apply_transpose(const float* __restrict__ x,
                                                          const float* __restrict__ mu,
                                                          const float* __restrict__ rs,
                                                          const float* __restrict__ lw,
                                                          const float* __restrict__ lb,
                                                          unsigned short* __restrict__ xtb,
                                                          float* __restrict__ partials) {
  __shared__ float tile[32 * 129];
  const int t0 = blockIdx.x * 32;
  const int c0 = blockIdx.y * 128;
  const int b = blockIdx.z;
  const int tid = threadIdx.x;
#pragma unroll
  for (int u = 0; u < 16; u++) {
    const int idx = tid + u * 256;
    const int row = idx >> 7, col = idx & 127;
    const int t = t0 + row;
    const float v = x[((size_t)(b * T_ + t)) * C_ + c0 + col];
    tile[row * 129 + col] = (v - mu[b * T_ + t]) * rs[b * T_ + t] * lw[c0 + col] + lb[c0 + col];
  }
  __syncthreads();
#pragma unroll
  for (int u = 0; u < 16; u++) {
    const int idx = tid + u * 256;
    const int cc = idx >> 5, tt = idx & 31;
    xtb[((size_t)(b * C_ + c0 + cc)) * T_ + t0 + tt] = bfbits(tile[tt * 129 + cc]);
  }
  if (tid < 128) {
    float s = 0.f;
#pragma unroll
    for (int tt = 0; tt < 32; tt++) s += tile[tt * 129 + tid];
    partials[((size_t)(b * C_ + c0 + tid)) * (T_ / 32) + blockIdx.x] = s;
  }
}

// ---------------------------------------------------------------------------
// K4: pooled[b,c] = sum of 128 tile partials. One wave per (b,c).
// ---------------------------------------------------------------------------
__global__ __launch_bounds__(256) void pool_finish(const float* __restrict__ partials,
                                                   float* __restrict__ pooled) {
  const int bc = blockIdx.x * 4 + (threadIdx.x >> 6);
  const int l = threadIdx.x & 63;
  const float2 v = ((const float2*)(partials + (size_t)bc * 128))[l];
  float s = v.x + v.y;
#pragma unroll
  for (int o = 32; o > 0; o >>= 1) s += __shfl_xor(s, o);
  if (l == 0) pooled[bc] = s;
}

// ---------------------------------------------------------------------------
// K5: scale[b,c] = gain[c] * sigmoid((pooled/T) @ Wctx + bctx)[b,c]
// ---------------------------------------------------------------------------
__global__ __launch_bounds__(256) void ctx_gate(const float* __restrict__ pooled,
                                                const float* __restrict__ W,
                                                const float* __restrict__ cb,
                                                const float* __restrict__ gain,
                                                float* __restrict__ scale) {
  const int b = blockIdx.y;
  const int c = blockIdx.x * 256 + threadIdx.x;
  __shared__ float pm[C_];
#pragma unroll
  for (int u = 0; u < 4; u++)
    pm[threadIdx.x + 256 * u] = pooled[b * C_ + threadIdx.x + 256 * u] * (1.0f / T_);
  __syncthreads();
  float a[8] = {0.f, 0.f, 0.f, 0.f, 0.f, 0.f, 0.f, 0.f};
  for (int k0 = 0; k0 < C_; k0 += 8) {
#pragma unroll
    for (int q = 0; q < 8; q++)
      a[q] = fmaf(pm[k0 + q], W[(size_t)(k0 + q) * C_ + c], a[q]);
  }
  const float z = a[0] + a[1] + a[2] + a[3] + a[4] + a[5] + a[6] + a[7] + cb[c];
  scale[b * C_ + c] = gain[c] * (1.0f / (1.0f + expf(-z)));
}

// ---------------------------------------------------------------------------
// K6: per-(b,c) column conv via radix-16 FFT (4096 = 16^3, 3 LDS stages).
// bf16 global I/O; f32 LDS/compute. (Radix-16 structure proven in R6.)
// ---------------------------------------------------------------------------
DEV int fft_addr(int i) { return i + (i >> 5) + (i >> 10); }   // injective (monotone)
DEV int rev16_3(int n) { return ((n & 15) << 8) | (n & 240) | (n >> 8); }  // involution

DEV void r4ip(float (&xr)[16], float (&xi)[16], const int s0, const int s1,
              const int s2, const int s3, const float SGN) {
  const float a0r = xr[s0] + xr[s2], a0i = xi[s0] + xi[s2];
  const float d0r = xr[s0] - xr[s2], d0i = xi[s0] - xi[s2];
  const float a1r = xr[s1] + xr[s3], a1i = xi[s1] + xi[s3];
  const float d1r = xr[s1] - xr[s3], d1i = xi[s1] - xi[s3];
  xr[s0] = a0r + a1r; xi[s0] = a0i + a1i;
  xr[s2] = a0r - a1r; xi[s2] = a0i - a1i;
  xr[s1] = d0r - SGN * d1i; xi[s1] = d0i + SGN * d1r;
  xr[s3] = d0r + SGN * d1i; xi[s3] = d0i - SGN * d1r;
}

// 16-pt DFT in registers. Output X[k] at slot 4*(k&3)+(k>>2).
// HALF: inputs q>=8 implicitly zero (forward stage 0 with zero-padding).
template <int INV, bool HALF>
DEV void dft16(float (&xr)[16], float (&xi)[16]) {
  constexpr float SGN = INV ? 1.0f : -1.0f;
  constexpr float C1 = 0.9238795325112867f, S1 = 0.3826834323650898f;
  constexpr float R2 = 0.7071067811865476f;
#pragma unroll
  for (int a = 0; a < 4; a++) {
    if constexpr (HALF) {
      const float ar = xr[a], ai = xi[a], br = xr[a + 4], bi = xi[a + 4];
      xr[a] = ar + br;             xi[a] = ai + bi;
      xr[a + 4] = ar - SGN * bi;   xi[a + 4] = ai + SGN * br;
      xr[a + 8] = ar - br;         xi[a + 8] = ai - bi;
      xr[a + 12] = ar + SGN * bi;  xi[a + 12] = ai - SGN * br;
    } else {
      r4ip(xr, xi, a, a + 4, a + 8, a + 12, SGN);
    }
  }
  auto tm = [&](int s, float wr, float wi) {
    const float t = xr[s] * wr - xi[s] * wi;
    xi[s] = xr[s] * wi + xi[s] * wr;
    xr[s] = t;
  };
  tm(5, C1, SGN * S1);
  tm(6, R2, SGN * R2);
  tm(7, S1, SGN * C1);
  tm(9, R2, SGN * R2);
  { const float t = -SGN * xi[10]; xi[10] = SGN * xr[10]; xr[10] = t; }
  tm(11, -R2, SGN * R2);
  tm(13, S1, SGN * C1);
  tm(14, -R2, SGN * R2);
  tm(15, -C1, -SGN * S1);
#pragma unroll
  for (int m = 0; m < 4; m++)
    r4ip(xr, xi, 4 * m + 0, 4 * m + 1, 4 * m + 2, 4 * m + 3, SGN);
}

template <int INV, int L, bool HALF>
DEV void fft_stage(float* sre, float* sim, const int g, const float2* __restrict__ twp) {
  constexpr float SGN = INV ? 1.0f : -1.0f;
  int base, pos;
  if constexpr (L == 1) { base = g << 4; pos = 0; }
  else if constexpr (L == 16) { base = ((g >> 4) << 8) | (g & 15); pos = g & 15; }
  else { base = g; pos = g; }
  float xr[16], xi[16];
#pragma unroll
  for (int q = 0; q < (HALF ? 8 : 16); q++) {
    const int idx = fft_addr(base + q * L);
    xr[q] = sre[idx]; xi[q] = sim[idx];
  }
  if constexpr (L > 1) {
    const float2* tp = twp + pos * 15;
#pragma unroll
    for (int q = 1; q < 16; q++) {
      const float2 w = tp[q - 1];
      const float wr = w.x, wi = SGN * w.y;
      const float t = xr[q] * wr - xi[q] * wi;
      xi[q] = xr[q] * wi + xi[q] * wr;
      xr[q] = t;
    }
  }
  dft16<INV, HALF>(xr, xi);
#pragma unroll
  for (int q = 0; q < 16; q++) {
    const int s = ((q & 3) << 2) | (q >> 2);
    const int idx = fft_addr(base + q * L);
    sre[idx] = xr[s]; sim[idx] = xi[s];
  }
}

__global__ __launch_bounds__(256) void fftconv(unsigned short* __restrict__ xtb,
                                               const float* __restrict__ keff,
                                               const float* __restrict__ scale,
                                               const float2* __restrict__ tw) {
  __shared__ float sre[4226];
  __shared__ float sim[4226];
  const int bc = blockIdx.x;
  const int tid = threadIdx.x;
  unsigned short* col = xtb + (size_t)bc * T_;
  const ushort2* c2 = (const ushort2*)col;
  const float2* k2 = (const float2*)keff;
  const float2* twu = tw + TW_UNT;

  // packed load: z[n] = x[2n] + i x[2n+1] (n<2048); n >= 2048 implicit zero.
#pragma unroll
  for (int u = 0; u < 8; u++) {
    const int n = tid + u * 256;
    const ushort2 v = c2[n];
    const int idx = fft_addr(rev16_3(n));
    sre[idx] = bf2f(v.x); sim[idx] = bf2f(v.y);
  }
  __syncthreads();
  fft_stage<0, 1, true>(sre, sim, tid, tw);
  __syncthreads();
  fft_stage<0, 16, false>(sre, sim, tid, tw + TW_S1);
  __syncthreads();
  fft_stage<0, 256, false>(sre, sim, tid, tw + TW_S2);
  __syncthreads();

  const float s = scale[bc] * (1.0f / 4096.0f);   // fold 1/N of inverse FFT
  float ozr[8], ozi[8], omr[8], omi[8];
#pragma unroll
  for (int u = 0; u < 8; u++) {
    const int k = tid + u * 256;
    if (k == 0) {
      const float z0r = sre[fft_addr(0)], z0i = sim[fft_addr(0)];
      const float zhr = sre[fft_addr(2048)], zhi = sim[fft_addr(2048)];
      const float X0 = z0r + z0i, XN = z0r - z0i;           // X[0], X[4096] (real)
      const float Y0 = X0 * keff[0] * s;
      const float YN = XN * keff[2 * 4096] * s;
      ozr[u] = 0.5f * (Y0 + YN); ozi[u] = 0.5f * (Y0 - YN); // Z'[0]
      const float gr = keff[2 * 2048] * s, gi = keff[2 * 2048 + 1] * s;
      const float Yr = zhr * gr + zhi * gi;                 // Y[2048] = conj(Z[2048])*G
      const float Yi = zhr * gi - zhi * gr;
      omr[u] = Yr; omi[u] = -Yi;                            // Z'[2048] = conj(Y)
    } else {
      const int m = 4096 - k;
      const float zkr = sre[fft_addr(k)], zki = sim[fft_addr(k)];
      const float zmr = sre[fft_addr(m)], zmi = sim[fft_addr(m)];
      const float Ar = 0.5f * (zkr + zmr), Ai = 0.5f * (zki - zmi);
      const float Br = 0.5f * (zki + zmi), Bi = 0.5f * (zmr - zkr);
      const float2 wc = twu[k];                             // e^{-i pi k/4096}
      const float cw = wc.x, sw = wc.y;
      const float Tr = Br * cw + Bi * sw, Ti = Bi * cw - Br * sw;
      const float X1r = Ar + Tr, X1i = Ai + Ti;             // X[k]
      const float X2r = Ar - Tr, X2i = Ti - Ai;             // X[N-k] = conj(A-T)
      const float2 g1 = k2[k], g2 = k2[m];
      const float g1r = g1.x * s, g1i = g1.y * s;
      const float g2r = g2.x * s, g2i = g2.y * s;
      const float Y1r = X1r * g1r - X1i * g1i, Y1i = X1r * g1i + X1i * g1r;
      const float Y2r = X2r * g2r - X2i * g2i, Y2i = X2r * g2i + X2i * g2r;
      const float A1r = 0.5f * (Y1r + Y2r), A1i = 0.5f * (Y1i - Y2i);
      const float Dr = 0.5f * (Y1r - Y2r), Di = 0.5f * (Y1i + Y2i);
      const float B1r = Dr * cw - Di * sw, B1i = Dr * sw + Di * cw;  // e^{+i pi k/N} * D
      ozr[u] = A1r - B1i; ozi[u] = A1i + B1r;   // Z'[k]   = A1 + i B1
      omr[u] = A1r + B1i; omi[u] = B1r - A1i;   // Z'[N-k] = conj(A1) + i conj(B1)
    }
  }
  __syncthreads();
#pragma unroll
  for (int u = 0; u < 8; u++) {
    const int k = tid + u * 256;
    const int m = (k == 0) ? 2048 : 4096 - k;
    const int rk = fft_addr(rev16_3(k)), rm = fft_addr(rev16_3(m));
    sre[rk] = ozr[u]; sim[rk] = ozi[u];
    sre[rm] = omr[u]; sim[rm] = omi[u];
  }
  __syncthreads();
  fft_stage<1, 1, false>(sre, sim, tid, tw);
  __syncthreads();
  fft_stage<1, 16, false>(sre, sim, tid, tw + TW_S1);
  __syncthreads();
  fft_stage<1, 256, false>(sre, sim, tid, tw + TW_S2);
  __syncthreads();

  ushort2* o2 = (ushort2*)col;   // y[2n]=Re z'[n], y[2n+1]=Im z'[n]; keep t<4096
#pragma unroll
  for (int u = 0; u < 8; u++) {
    const int n = tid + u * 256;
    o2[n] = make_ushort2(bfbits(sre[fft_addr(n)]), bfbits(sim[fft_addr(n)]));
  }
}

// ---------------------------------------------------------------------------
// K7: out[b,t,c] = x[b,t,c] + y_t[b,c,t]  (bf16 yt, transpose back + residual)
// ---------------------------------------------------------------------------
__global__ __launch_bounds__(256) void add_residual_transpose(const float* __restrict__ x,
                                                              const unsigned short* __restrict__ ytb,
                                                              float* __restrict__ out) {
  __shared__ float tile[32 * 129];
  const int t0 = blockIdx.x * 128;
  const int c0 = blockIdx.y * 32;
  const int b = blockIdx.z;
  const int tid = threadIdx.x;
#pragma unroll
  for (int u = 0; u < 4; u++) {
    const int idx4 = tid + u * 256;
    const int cr = idx4 >> 5, tq = idx4 & 31;
    const ushort4 v = *(const ushort4*)(ytb + ((size_t)(b * C_ + c0 + cr)) * T_ + t0 + tq * 4);
    tile[cr * 129 + tq * 4 + 0] = bf2f(v.x);
    tile[cr * 129 + tq * 4 + 1] = bf2f(v.y);
    tile[cr * 129 + tq * 4 + 2] = bf2f(v.z);
    tile[cr * 129 + tq * 4 + 3] = bf2f(v.w);
  }
  __syncthreads();
#pragma unroll
  for (int u = 0; u < 16; u++) {
    const int idx = tid + u * 256;
    const int tr = idx >> 5, cc = idx & 31;
    const size_t o = ((size_t)(b * T_ + t0 + tr)) * C_ + c0 + cc;
    out[o] = x[o] + tile[cc * 129 + tr];
  }
}

// ---------------------------------------------------------------------------
// K8: fused LN over x2 rows -> bf16 ff_in. One wave per row, values in regs.
// ---------------------------------------------------------------------------
__global__ __launch_bounds__(256) void ln2_apply(const float* __restrict__ x2,
                                                 const float* __restrict__ lw,
                                                 const float* __restrict__ lb,
                                                 hb* __restrict__ outb) {
  const int row = blockIdx.x * 4 + (threadIdx.x >> 6);
  const int l = threadIdx.x & 63;
  const float4* p = (const float4*)(x2 + (size_t)row * C_);
  float4 v[4];
  float s = 0.f, sq = 0.f;
#pragma unroll
  for (int u = 0; u < 4; u++) {
    v[u] = p[l + 64 * u];
    s += v[u].x + v[u].y + v[u].z + v[u].w;
    sq += v[u].x * v[u].x + v[u].y * v[u].y + v[u].z * v[u].z + v[u].w * v[u].w;
  }
#pragma unroll
  for (int o = 32; o > 0; o >>= 1) { s += __shfl_xor(s, o); sq += __shfl_xor(sq, o); }
  const float m = s * (1.0f / C_);
  const float r = rsqrtf(sq * (1.0f / C_) - m * m + EPS_);
  ushort4* ob = (ushort4*)(outb + (size_t)row * C_);
  const float4* wp = (const float4*)lw;
  const float4* bp = (const float4*)lb;
#pragma unroll
  for (int u = 0; u < 4; u++) {
    const float4 w4 = wp[l + 64 * u], b4 = bp[l + 64 * u];
    ushort4 o4;
    o4.x = bfbits((v[u].x - m) * r * w4.x + b4.x);
    o4.y = bfbits((v[u].y - m) * r * w4.y + b4.y);
    o4.z = bfbits((v[u].z - m) * r * w4.z + b4.z);
    o4.w = bfbits((v[u].w - m) * r * w4.w + b4.w);
    ob[l + 64 * u] = o4;
  }
}

// ---------------------------------------------------------------------------
// K9/K10: transpose f32 [R][Cc] -> bf16 [Cc][R]
// ---------------------------------------------------------------------------
__global__ __launch_bounds__(256) void transpose_cast(const float* __restrict__ src,
                                                      hb* __restrict__ dst,
                                                      int R, int Cc) {
  __shared__ float tile[32 * 33];
  const int c0 = blockIdx.x * 32, r0 = blockIdx.y * 32;
  const int tid = threadIdx.x;
#pragma unroll
  for (int u = 0; u < 4; u++) {
    const int idx = tid + u * 256;
    const int r = idx >> 5, c = idx & 31;
    tile[r * 33 + c] = src[(size_t)(r0 + r) * Cc + c0 + c];
  }
  __syncthreads();
#pragma unroll
  for (int u = 0; u < 4; u++) {
    const int idx = tid + u * 256;
    const int c = idx >> 5, r = idx & 31;
    dst[(size_t)(c0 + c) * R + r0 + r] = __float2bfloat16(tile[r * 33 + c]);
  }
}

// ---------------------------------------------------------------------------
// K11/K12: bf16 MFMA GEMM, 128x128 tile, BK=64, 4 waves, T3-minimum 2-phase:
// double-buffered LDS (64KB -> 2 blocks/CU), stage(t+1) issued BEFORE
// compute(t), one barrier per K-tile. Conflict-free XOR involution swizzle
// (both sides) + bijective XCD swizzle + fast sigmoid-GELU.
// ---------------------------------------------------------------------------
template <int EPI, int NG, int KG>
__global__ __launch_bounds__(256, 4) void gemm_k(const unsigned short* __restrict__ A,
                                                 const unsigned short* __restrict__ Bm,
                                                 const float* __restrict__ bias,
                                                 float* __restrict__ outf,
                                                 hb* __restrict__ outh) {
  __shared__ __align__(16) unsigned short As[2][128 * 64];
  __shared__ __align__(16) unsigned short Bs[2][128 * 64];
  constexpr int GN = NG / 128;
  constexpr int NT = KG / 64;
  const int nwg = (BT_ / 128) * GN;
  const int bid = blockIdx.x;
  const int wg = (bid & 7) * (nwg >> 3) + (bid >> 3);   // bijective XCD swizzle
  const int m0 = (wg / GN) * 128, n0 = (wg % GN) * 128;
  const int tid = threadIdx.x;
  const int r = tid >> 3, sl = tid & 7;
  const int l = tid & 63, wv = tid >> 6;
  const int wm = wv >> 1, wn = wv & 1;
  const int lr = l & 15, lq = l >> 4;

  f32x4 acc[4][4];
#pragma unroll
  for (int i = 0; i < 4; i++)
#pragma unroll
    for (int j = 0; j < 4; j++) acc[i][j] = f32x4{0.f, 0.f, 0.f, 0.f};

  auto stage = [&](int d, int k0) {
#pragma unroll
    for (int ch = 0; ch < 4; ch++) {
      const int row = ch * 32 + r;
      const int slot = sl ^ (row & 7);                  // inverse-swizzled source
      gload16(A + (size_t)(m0 + row) * KG + k0 + slot * 8, &As[d][ch * 2048 + tid * 8]);
      gload16(Bm + (size_t)(n0 + row) * KG + k0 + slot * 8, &Bs[d][ch * 2048 + tid * 8]);
    }
  };
  auto compute = [&](int d) {
#pragma unroll
    for (int ks = 0; ks < 2; ks++) {
      bf16x8 av[4], bv[4];
#pragma unroll
      for (int i = 0; i < 4; i++) {
        const int row = wm * 64 + i * 16 + lr;
        av[i] = *reinterpret_cast<const bf16x8*>(&As[d][row * 64 + (((ks * 4 + lq) ^ (row & 7)) * 8)]);
      }
#pragma unroll
      for (int j = 0; j < 4; j++) {
        const int row = wn * 64 + j * 16 + lr;
        bv[j] = *reinterpret_cast<const bf16x8*>(&Bs[d][row * 64 + (((ks * 4 + lq) ^ (row & 7)) * 8)]);
      }
#pragma unroll
      for (int i = 0; i < 4; i++)
#pragma unroll
        for (int j = 0; j < 4; j++)
          acc[i][j] = __builtin_amdgcn_mfma_f32_16x16x32_bf16(av[i], bv[j], acc[i][j], 0, 0, 0);
    }
  };

  stage(0, 0);
  __syncthreads();
  for (int t = 0; t < NT; t++) {
    if (t + 1 < NT) stage((t + 1) & 1, (t + 1) * 64);   // loads fly under compute
    compute(t & 1);
    __syncthreads();                                    // drains vmcnt, swaps buffers
  }

#pragma unroll
  for (int i = 0; i < 4; i++) {
#pragma unroll
    for (int j = 0; j < 4; j++) {
      const int n = n0 + wn * 64 + j * 16 + lr;
      const float bn = bias[n];
#pragma unroll
      for (int rr = 0; rr < 4; rr++) {
        const int m = m0 + wm * 64 + i * 16 + lq * 4 + rr;
        const float v = acc[i][j][rr] + bn;
        if constexpr (EPI == 0) {
          const float u = 1.5957691216f * fmaf(0.044715f * v, v * v, v);
          const float ge = v / (1.0f + __expf(-u));
          outh[(size_t)m * NG + n] = __float2bfloat16(ge);
        } else {
          outf[(size_t)m * NG + n] += v;
        }
      }
    }
  }
}

// ---------------------------------------------------------------------------
extern "C" void kernel_launch(void* const* d_in, const int* in_sizes, int n_in,
                              void* d_out, int out_size, void* d_ws, size_t ws_size,
                              hipStream_t stream) {
  (void)in_sizes; (void)n_in; (void)out_size; (void)ws_size;
  const float* x    = (const float*)d_in[0];
  const float* kern = (const float*)d_in[1];
  const float* gain = (const float*)d_in[2];
  const float* gfl  = (const float*)d_in[3];
  const float* gcw  = (const float*)d_in[4];
  const float* gcb  = (const float*)d_in[5];
  const float* lnw  = (const float*)d_in[6];
  const float* lnb  = (const float*)d_in[7];
  const float* flnw = (const float*)d_in[8];
  const float* flnb = (const float*)d_in[9];
  const float* w1   = (const float*)d_in[10];
  const float* b1   = (const float*)d_in[11];
  const float* w2   = (const float*)d_in[12];
  const float* b2   = (const float*)d_in[13];
  const int*   cut  = (const int*)d_in[14];
  float* out = (float*)d_out;

  char* ws = (char*)d_ws;
  size_t off = 0;
  auto alloc = [&](size_t bytes) -> void* {
    void* p = ws + off;
    off += (bytes + 255) & ~(size_t)255;
    return p;
  };
  unsigned short* xtb = (unsigned short*)alloc((size_t)B_ * C_ * T_ * 2);  // 32MB bf16
  hb*    ffin   = (hb*)alloc((size_t)BT_ * C_ * 2);          // 32MB
  hb*    hbuf   = (hb*)alloc((size_t)BT_ * H_ * 2);          // 64MB
  hb*    w1t    = (hb*)alloc((size_t)H_ * C_ * 2);           // 4MB
  hb*    w2t    = (hb*)alloc((size_t)C_ * H_ * 2);           // 4MB
  float* keff   = (float*)alloc((size_t)FB * 2 * 4);
  float* mu     = (float*)alloc((size_t)BT_ * 4);
  float* rs     = (float*)alloc((size_t)BT_ * 4);
  float* parts  = (float*)alloc((size_t)B_ * C_ * (T_ / 32) * 4);  // 2MB
  float* pooled = (float*)alloc((size_t)B_ * C_ * 4);
  float* scale  = (float*)alloc((size_t)B_ * C_ * 4);
  float2* tw    = (float2*)alloc((size_t)TW_TOTAL * 8);      // 48KB twiddles

  build_tw<<<(TW_TOTAL + 255) / 256, 256, 0, stream>>>(tw);
  build_keff<<<FB, 256, 0, stream>>>(kern, gfl, cut, keff);
  ln_stats<<<BT_ / 4, 256, 0, stream>>>(x, mu, rs);
  ln_apply_transpose<<<dim3(T_ / 32, C_ / 128, B_), 256, 0, stream>>>(x, mu, rs, lnw, lnb, xtb, parts);
  pool_finish<<<B_ * C_ / 4, 256, 0, stream>>>(parts, pooled);
  ctx_gate<<<dim3(C_ / 256, B_), 256, 0, stream>>>(pooled, gcw, gcb, gain, scale);
  fftconv<<<B_ * C_, 256, 0, stream>>>(xtb, keff, scale, tw);
  add_residual_transpose<<<dim3(T_ / 128, C_ / 32, B_), 256, 0, stream>>>(x, xtb, out);
  ln2_apply<<<BT_ / 4, 256, 0, stream>>>(out, flnw, flnb, ffin);
  transpose_cast<<<dim3(H_ / 32, C_ / 32), 256, 0, stream>>>(w1, w1t, C_, H_);
  transpose_cast<<<dim3(C_ / 32, H_ / 32), 256, 0, stream>>>(w2, w2t, H_, C_);
  gemm_k<0, H_, C_><<<(BT_ / 128) * (H_ / 128), 256, 0, stream>>>(
      (const unsigned short*)ffin, (const unsigned short*)w1t, b1, nullptr, hbuf);
  gemm_k<1, C_, H_><<<(BT_ / 128) * (C_ / 128), 256, 0, stream>>>(
      (const unsigned short*)hbuf, (const unsigned short*)w2t, b2, out, nullptr);
}

// Round 8
// 369.727 us; speedup vs baseline: 1.1227x; 1.1227x over previous
//
#include <hip/hip_runtime.h>
#include <hip/hip_bf16.h>
#include <cstdint>
#include <cstddef>

#define DEV static __device__ __forceinline__

typedef __hip_bfloat16 hb;
typedef __bf16 bf16x8 __attribute__((ext_vector_type(8)));
typedef float f32x4 __attribute__((ext_vector_type(4)));
typedef __attribute__((address_space(1))) unsigned int as1_u32;
typedef __attribute__((address_space(3))) unsigned int as3_u32;

constexpr int B_ = 4, T_ = 4096, C_ = 1024, NFFT = 8192, FB = 4097, H_ = 2048;
constexpr int BT_ = B_ * T_;
constexpr float EPS_ = 1e-5f;
constexpr int TRANS_ = 16;
// twiddle table: [0,240) stage L=16; [240,4080) stage L=256; [4080,6128) untangle.
constexpr int TW_S1 = 0;
constexpr int TW_S2 = 240;
constexpr int TW_UNT = 4080;
constexpr int TW_TOTAL = 6128;

DEV void gload16(const void* gsrc, void* ldst) {
  __builtin_amdgcn_global_load_lds((as1_u32*)gsrc, (as3_u32*)ldst, 16, 0, 0);
}

DEV unsigned short bfbits(float f) {
  hb h = __float2bfloat16(f);
  return __builtin_bit_cast(unsigned short, h);
}
DEV float bf2f(unsigned short u) {
  unsigned int x = ((unsigned int)u) << 16;
  return __builtin_bit_cast(float, x);
}

// ---------------------------------------------------------------------------
// K0: twiddle tables (shared by all fftconv blocks; L2-resident).
// ---------------------------------------------------------------------------
__global__ __launch_bounds__(256) void build_tw(float2* __restrict__ tw) {
  const int i = blockIdx.x * 256 + threadIdx.x;
  if (i < 240) {                        // stage L=16: W_256^{pq}
    const int pos = i / 15, q = i % 15 + 1;
    float sn, cs;
    sincospif((float)(pos * q) * (1.0f / 128.0f), &sn, &cs);
    tw[i] = make_float2(cs, sn);
  } else if (i < 4080) {                // stage L=256: W_4096^{pq}
    const int j = i - 240;
    const int pos = j / 15, q = j % 15 + 1;
    float sn, cs;
    sincospif((float)(pos * q) * (1.0f / 2048.0f), &sn, &cs);
    tw[i] = make_float2(cs, sn);
  } else if (i < TW_TOTAL) {            // untangle: e^{-i pi k/4096}
    const int k = i - TW_UNT;
    float sn, cs;
    sincospif((float)k * (1.0f / 4096.0f), &sn, &cs);
    tw[i] = make_float2(cs, sn);
  }
}

// ---------------------------------------------------------------------------
// K1: keff[f] = rfft(kernel,8192)[f] * sigmoid(logits[f]) * mask(f, cutoff)
// ---------------------------------------------------------------------------
__global__ __launch_bounds__(256) void build_keff(const float* __restrict__ kern,
                                                  const float* __restrict__ logits,
                                                  const int* __restrict__ cutp,
                                                  float* __restrict__ keff) {
  const int f = blockIdx.x;      // 0..4096
  const int tid = threadIdx.x;
  float sr = 0.f, si = 0.f;
#pragma unroll
  for (int u = 0; u < 4; u++) {
    const int k = tid + u * 256;
    const float kv = kern[k];
    const int m = (f * k) & (NFFT - 1);      // exact phase mod 8192
    float sn, cs;
    sincospif((float)m * (1.0f / 4096.0f), &sn, &cs);  // e^{-2pi i m/8192}
    sr = fmaf(kv, cs, sr);
    si = fmaf(kv, -sn, si);
  }
#pragma unroll
  for (int o = 32; o > 0; o >>= 1) { sr += __shfl_xor(sr, o); si += __shfl_xor(si, o); }
  __shared__ float redr[4], redi[4];
  if ((tid & 63) == 0) { redr[tid >> 6] = sr; redi[tid >> 6] = si; }
  __syncthreads();
  if (tid == 0) {
    float kr = redr[0] + redr[1] + redr[2] + redr[3];
    float ki = redi[0] + redi[1] + redi[2] + redi[3];
    const float g = 1.0f / (1.0f + expf(-logits[f]));
    int cc = *cutp; if (cc > FB) cc = FB;
    float msk = 1.0f;
    if (cc < FB) {                           // mask active (None-case otherwise)
      int tr = TRANS_ < cc ? TRANS_ : cc;
      if (f >= cc) msk = 0.0f;
      else if (f >= cc - tr) {
        int i = f - (cc - tr);
        int den = (tr > 1) ? (tr - 1) : 1;
        msk = 0.5f * (1.0f + cospif((float)i / (float)den));
      }
    }
    const float gm = g * msk;
    keff[2 * f] = kr * gm;
    keff[2 * f + 1] = ki * gm;
  }
}

// ---------------------------------------------------------------------------
// K2: per-row LayerNorm stats (mean, rstd) over C. One wave per row.
// ---------------------------------------------------------------------------
__global__ __launch_bounds__(256) void ln_stats(const float* __restrict__ x,
                                                float* __restrict__ mu,
                                                float* __restrict__ rs) {
  const int row = blockIdx.x * 4 + (threadIdx.x >> 6);
  const int l = threadIdx.x & 63;
  const float4* p = (const float4*)(x + (size_t)row * C_);
  float s = 0.f, sq = 0.f;
#pragma unroll
  for (int u = 0; u < 4; u++) {
    float4 v = p[l + 64 * u];
    s += v.x + v.y + v.z + v.w;
    sq += v.x * v.x + v.y * v.y + v.z * v.z + v.w * v.w;
  }
#pragma unroll
  for (int o = 32; o > 0; o >>= 1) { s += __shfl_xor(s, o); sq += __shfl_xor(sq, o); }
  if (l == 0) {
    float m = s * (1.0f / C_);
    float var = sq * (1.0f / C_) - m * m;
    mu[row] = m;
    rs[row] = rsqrtf(var + EPS_);
  }
}

// ---------------------------------------------------------------------------
// K3: apply LN, transpose [B,T,C] -> bf16 [B,C,T], emit per-tile column sums
// (pooled partials from the f32 values, so g_ctx precision is unchanged).
// ---------------------------------------------------------------------------
__global__ __launch_bounds__(256) void ln_apply_transpose(const float* __restrict__ x,
                                                          const float* __restrict__ mu,
                                                          const float* __restrict__ rs,
                                                          const float* __restrict__ lw,
                                                          const float* __restrict__ lb,
                                                          unsigned short* __restrict__ xtb,
                                                          float* __restrict__ partials) {
  __shared__ float tile[32 * 129];
  const int t0 = blockIdx.x * 32;
  const int c0 = blockIdx.y * 128;
  const int b = blockIdx.z;
  const int tid = threadIdx.x;
#pragma unroll
  for (int u = 0; u < 16; u++) {
    const int idx = tid + u * 256;
    const int row = idx >> 7, col = idx & 127;
    const int t = t0 + row;
    const float v = x[((size_t)(b * T_ + t)) * C_ + c0 + col];
    tile[row * 129 + col] = (v - mu[b * T_ + t]) * rs[b * T_ + t] * lw[c0 + col] + lb[c0 + col];
  }
  __syncthreads();
#pragma unroll
  for (int u = 0; u < 16; u++) {
    const int idx = tid + u * 256;
    const int cc = idx >> 5, tt = idx & 31;
    xtb[((size_t)(b * C_ + c0 + cc)) * T_ + t0 + tt] = bfbits(tile[tt * 129 + cc]);
  }
  if (tid < 128) {
    float s = 0.f;
#pragma unroll
    for (int tt = 0; tt < 32; tt++) s += tile[tt * 129 + tid];
    partials[((size_t)(b * C_ + c0 + tid)) * (T_ / 32) + blockIdx.x] = s;
  }
}

// ---------------------------------------------------------------------------
// K4: pooled[b,c] = sum of 128 tile partials. One wave per (b,c).
// ---------------------------------------------------------------------------
__global__ __launch_bounds__(256) void pool_finish(const float* __restrict__ partials,
                                                   float* __restrict__ pooled) {
  const int bc = blockIdx.x * 4 + (threadIdx.x >> 6);
  const int l = threadIdx.x & 63;
  const float2 v = ((const float2*)(partials + (size_t)bc * 128))[l];
  float s = v.x + v.y;
#pragma unroll
  for (int o = 32; o > 0; o >>= 1) s += __shfl_xor(s, o);
  if (l == 0) pooled[bc] = s;
}

// ---------------------------------------------------------------------------
// K5: scale[b,c] = gain[c] * sigmoid((pooled/T) @ Wctx + bctx)[b,c]
// ---------------------------------------------------------------------------
__global__ __launch_bounds__(256) void ctx_gate(const float* __restrict__ pooled,
                                                const float* __restrict__ W,
                                                const float* __restrict__ cb,
                                                const float* __restrict__ gain,
                                                float* __restrict__ scale) {
  const int b = blockIdx.y;
  const int c = blockIdx.x * 256 + threadIdx.x;
  __shared__ float pm[C_];
#pragma unroll
  for (int u = 0; u < 4; u++)
    pm[threadIdx.x + 256 * u] = pooled[b * C_ + threadIdx.x + 256 * u] * (1.0f / T_);
  __syncthreads();
  float a[8] = {0.f, 0.f, 0.f, 0.f, 0.f, 0.f, 0.f, 0.f};
  for (int k0 = 0; k0 < C_; k0 += 8) {
#pragma unroll
    for (int q = 0; q < 8; q++)
      a[q] = fmaf(pm[k0 + q], W[(size_t)(k0 + q) * C_ + c], a[q]);
  }
  const float z = a[0] + a[1] + a[2] + a[3] + a[4] + a[5] + a[6] + a[7] + cb[c];
  scale[b * C_ + c] = gain[c] * (1.0f / (1.0f + expf(-z)));
}

// ---------------------------------------------------------------------------
// K6: per-(b,c) column conv via radix-16 FFT (4096 = 16^3, 3 LDS stages).
// bf16 global I/O; f32 LDS/compute. (Radix-16 structure proven in R6.)
// ---------------------------------------------------------------------------
DEV int fft_addr(int i) { return i + (i >> 5) + (i >> 10); }   // injective (monotone)
DEV int rev16_3(int n) { return ((n & 15) << 8) | (n & 240) | (n >> 8); }  // involution

DEV void r4ip(float (&xr)[16], float (&xi)[16], const int s0, const int s1,
              const int s2, const int s3, const float SGN) {
  const float a0r = xr[s0] + xr[s2], a0i = xi[s0] + xi[s2];
  const float d0r = xr[s0] - xr[s2], d0i = xi[s0] - xi[s2];
  const float a1r = xr[s1] + xr[s3], a1i = xi[s1] + xi[s3];
  const float d1r = xr[s1] - xr[s3], d1i = xi[s1] - xi[s3];
  xr[s0] = a0r + a1r; xi[s0] = a0i + a1i;
  xr[s2] = a0r - a1r; xi[s2] = a0i - a1i;
  xr[s1] = d0r - SGN * d1i; xi[s1] = d0i + SGN * d1r;
  xr[s3] = d0r + SGN * d1i; xi[s3] = d0i - SGN * d1r;
}

// 16-pt DFT in registers. Output X[k] at slot 4*(k&3)+(k>>2).
// HALF: inputs q>=8 implicitly zero (forward stage 0 with zero-padding).
template <int INV, bool HALF>
DEV void dft16(float (&xr)[16], float (&xi)[16]) {
  constexpr float SGN = INV ? 1.0f : -1.0f;
  constexpr float C1 = 0.9238795325112867f, S1 = 0.3826834323650898f;
  constexpr float R2 = 0.7071067811865476f;
#pragma unroll
  for (int a = 0; a < 4; a++) {
    if constexpr (HALF) {
      const float ar = xr[a], ai = xi[a], br = xr[a + 4], bi = xi[a + 4];
      xr[a] = ar + br;             xi[a] = ai + bi;
      xr[a + 4] = ar - SGN * bi;   xi[a + 4] = ai + SGN * br;
      xr[a + 8] = ar - br;         xi[a + 8] = ai - bi;
      xr[a + 12] = ar + SGN * bi;  xi[a + 12] = ai - SGN * br;
    } else {
      r4ip(xr, xi, a, a + 4, a + 8, a + 12, SGN);
    }
  }
  auto tm = [&](int s, float wr, float wi) {
    const float t = xr[s] * wr - xi[s] * wi;
    xi[s] = xr[s] * wi + xi[s] * wr;
    xr[s] = t;
  };
  tm(5, C1, SGN * S1);
  tm(6, R2, SGN * R2);
  tm(7, S1, SGN * C1);
  tm(9, R2, SGN * R2);
  { const float t = -SGN * xi[10]; xi[10] = SGN * xr[10]; xr[10] = t; }
  tm(11, -R2, SGN * R2);
  tm(13, S1, SGN * C1);
  tm(14, -R2, SGN * R2);
  tm(15, -C1, -SGN * S1);
#pragma unroll
  for (int m = 0; m < 4; m++)
    r4ip(xr, xi, 4 * m + 0, 4 * m + 1, 4 * m + 2, 4 * m + 3, SGN);
}

template <int INV, int L, bool HALF>
DEV void fft_stage(float* sre, float* sim, const int g, const float2* __restrict__ twp) {
  constexpr float SGN = INV ? 1.0f : -1.0f;
  int base, pos;
  if constexpr (L == 1) { base = g << 4; pos = 0; }
  else if constexpr (L == 16) { base = ((g >> 4) << 8) | (g & 15); pos = g & 15; }
  else { base = g; pos = g; }
  float xr[16], xi[16];
#pragma unroll
  for (int q = 0; q < (HALF ? 8 : 16); q++) {
    const int idx = fft_addr(base + q * L);
    xr[q] = sre[idx]; xi[q] = sim[idx];
  }
  if constexpr (L > 1) {
    const float2* tp = twp + pos * 15;
#pragma unroll
    for (int q = 1; q < 16; q++) {
      const float2 w = tp[q - 1];
      const float wr = w.x, wi = SGN * w.y;
      const float t = xr[q] * wr - xi[q] * wi;
      xi[q] = xr[q] * wi + xi[q] * wr;
      xr[q] = t;
    }
  }
  dft16<INV, HALF>(xr, xi);
#pragma unroll
  for (int q = 0; q < 16; q++) {
    const int s = ((q & 3) << 2) | (q >> 2);
    const int idx = fft_addr(base + q * L);
    sre[idx] = xr[s]; sim[idx] = xi[s];
  }
}

__global__ __launch_bounds__(256) void fftconv(unsigned short* __restrict__ xtb,
                                               const float* __restrict__ keff,
                                               const float* __restrict__ scale,
                                               const float2* __restrict__ tw) {
  __shared__ float sre[4226];
  __shared__ float sim[4226];
  const int bc = blockIdx.x;
  const int tid = threadIdx.x;
  unsigned short* col = xtb + (size_t)bc * T_;
  const ushort2* c2 = (const ushort2*)col;
  const float2* k2 = (const float2*)keff;
  const float2* twu = tw + TW_UNT;

  // packed load: z[n] = x[2n] + i x[2n+1] (n<2048); n >= 2048 implicit zero.
#pragma unroll
  for (int u = 0; u < 8; u++) {
    const int n = tid + u * 256;
    const ushort2 v = c2[n];
    const int idx = fft_addr(rev16_3(n));
    sre[idx] = bf2f(v.x); sim[idx] = bf2f(v.y);
  }
  __syncthreads();
  fft_stage<0, 1, true>(sre, sim, tid, tw);
  __syncthreads();
  fft_stage<0, 16, false>(sre, sim, tid, tw + TW_S1);
  __syncthreads();
  fft_stage<0, 256, false>(sre, sim, tid, tw + TW_S2);
  __syncthreads();

  const float s = scale[bc] * (1.0f / 4096.0f);   // fold 1/N of inverse FFT
  float ozr[8], ozi[8], omr[8], omi[8];
#pragma unroll
  for (int u = 0; u < 8; u++) {
    const int k = tid + u * 256;
    if (k == 0) {
      const float z0r = sre[fft_addr(0)], z0i = sim[fft_addr(0)];
      const float zhr = sre[fft_addr(2048)], zhi = sim[fft_addr(2048)];
      const float X0 = z0r + z0i, XN = z0r - z0i;           // X[0], X[4096] (real)
      const float Y0 = X0 * keff[0] * s;
      const float YN = XN * keff[2 * 4096] * s;
      ozr[u] = 0.5f * (Y0 + YN); ozi[u] = 0.5f * (Y0 - YN); // Z'[0]
      const float gr = keff[2 * 2048] * s, gi = keff[2 * 2048 + 1] * s;
      const float Yr = zhr * gr + zhi * gi;                 // Y[2048] = conj(Z[2048])*G
      const float Yi = zhr * gi - zhi * gr;
      omr[u] = Yr; omi[u] = -Yi;                            // Z'[2048] = conj(Y)
    } else {
      const int m = 4096 - k;
      const float zkr = sre[fft_addr(k)], zki = sim[fft_addr(k)];
      const float zmr = sre[fft_addr(m)], zmi = sim[fft_addr(m)];
      const float Ar = 0.5f * (zkr + zmr), Ai = 0.5f * (zki - zmi);
      const float Br = 0.5f * (zki + zmi), Bi = 0.5f * (zmr - zkr);
      const float2 wc = twu[k];                             // e^{-i pi k/4096}
      const float cw = wc.x, sw = wc.y;
      const float Tr = Br * cw + Bi * sw, Ti = Bi * cw - Br * sw;
      const float X1r = Ar + Tr, X1i = Ai + Ti;             // X[k]
      const float X2r = Ar - Tr, X2i = Ti - Ai;             // X[N-k] = conj(A-T)
      const float2 g1 = k2[k], g2 = k2[m];
      const float g1r = g1.x * s, g1i = g1.y * s;
      const float g2r = g2.x * s, g2i = g2.y * s;
      const float Y1r = X1r * g1r - X1i * g1i, Y1i = X1r * g1i + X1i * g1r;
      const float Y2r = X2r * g2r - X2i * g2i, Y2i = X2r * g2i + X2i * g2r;
      const float A1r = 0.5f * (Y1r + Y2r), A1i = 0.5f * (Y1i - Y2i);
      const float Dr = 0.5f * (Y1r - Y2r), Di = 0.5f * (Y1i + Y2i);
      const float B1r = Dr * cw - Di * sw, B1i = Dr * sw + Di * cw;  // e^{+i pi k/N} * D
      ozr[u] = A1r - B1i; ozi[u] = A1i + B1r;   // Z'[k]   = A1 + i B1
      omr[u] = A1r + B1i; omi[u] = B1r - A1i;   // Z'[N-k] = conj(A1) + i conj(B1)
    }
  }
  __syncthreads();
#pragma unroll
  for (int u = 0; u < 8; u++) {
    const int k = tid + u * 256;
    const int m = (k == 0) ? 2048 : 4096 - k;
    const int rk = fft_addr(rev16_3(k)), rm = fft_addr(rev16_3(m));
    sre[rk] = ozr[u]; sim[rk] = ozi[u];
    sre[rm] = omr[u]; sim[rm] = omi[u];
  }
  __syncthreads();
  fft_stage<1, 1, false>(sre, sim, tid, tw);
  __syncthreads();
  fft_stage<1, 16, false>(sre, sim, tid, tw + TW_S1);
  __syncthreads();
  fft_stage<1, 256, false>(sre, sim, tid, tw + TW_S2);
  __syncthreads();

  ushort2* o2 = (ushort2*)col;   // y[2n]=Re z'[n], y[2n+1]=Im z'[n]; keep t<4096
#pragma unroll
  for (int u = 0; u < 8; u++) {
    const int n = tid + u * 256;
    o2[n] = make_ushort2(bfbits(sre[fft_addr(n)]), bfbits(sim[fft_addr(n)]));
  }
}

// ---------------------------------------------------------------------------
// K7: out[b,t,c] = x[b,t,c] + y_t[b,c,t]  (bf16 yt, transpose back + residual)
// ---------------------------------------------------------------------------
__global__ __launch_bounds__(256) void add_residual_transpose(const float* __restrict__ x,
                                                              const unsigned short* __restrict__ ytb,
                                                              float* __restrict__ out) {
  __shared__ float tile[32 * 129];
  const int t0 = blockIdx.x * 128;
  const int c0 = blockIdx.y * 32;
  const int b = blockIdx.z;
  const int tid = threadIdx.x;
#pragma unroll
  for (int u = 0; u < 4; u++) {
    const int idx4 = tid + u * 256;
    const int cr = idx4 >> 5, tq = idx4 & 31;
    const ushort4 v = *(const ushort4*)(ytb + ((size_t)(b * C_ + c0 + cr)) * T_ + t0 + tq * 4);
    tile[cr * 129 + tq * 4 + 0] = bf2f(v.x);
    tile[cr * 129 + tq * 4 + 1] = bf2f(v.y);
    tile[cr * 129 + tq * 4 + 2] = bf2f(v.z);
    tile[cr * 129 + tq * 4 + 3] = bf2f(v.w);
  }
  __syncthreads();
#pragma unroll
  for (int u = 0; u < 16; u++) {
    const int idx = tid + u * 256;
    const int tr = idx >> 5, cc = idx & 31;
    const size_t o = ((size_t)(b * T_ + t0 + tr)) * C_ + c0 + cc;
    out[o] = x[o] + tile[cc * 129 + tr];
  }
}

// ---------------------------------------------------------------------------
// K8: fused LN over x2 rows -> bf16 ff_in. One wave per row, values in regs.
// ---------------------------------------------------------------------------
__global__ __launch_bounds__(256) void ln2_apply(const float* __restrict__ x2,
                                                 const float* __restrict__ lw,
                                                 const float* __restrict__ lb,
                                                 hb* __restrict__ outb) {
  const int row = blockIdx.x * 4 + (threadIdx.x >> 6);
  const int l = threadIdx.x & 63;
  const float4* p = (const float4*)(x2 + (size_t)row * C_);
  float4 v[4];
  float s = 0.f, sq = 0.f;
#pragma unroll
  for (int u = 0; u < 4; u++) {
    v[u] = p[l + 64 * u];
    s += v[u].x + v[u].y + v[u].z + v[u].w;
    sq += v[u].x * v[u].x + v[u].y * v[u].y + v[u].z * v[u].z + v[u].w * v[u].w;
  }
#pragma unroll
  for (int o = 32; o > 0; o >>= 1) { s += __shfl_xor(s, o); sq += __shfl_xor(sq, o); }
  const float m = s * (1.0f / C_);
  const float r = rsqrtf(sq * (1.0f / C_) - m * m + EPS_);
  ushort4* ob = (ushort4*)(outb + (size_t)row * C_);
  const float4* wp = (const float4*)lw;
  const float4* bp = (const float4*)lb;
#pragma unroll
  for (int u = 0; u < 4; u++) {
    const float4 w4 = wp[l + 64 * u], b4 = bp[l + 64 * u];
    ushort4 o4;
    o4.x = bfbits((v[u].x - m) * r * w4.x + b4.x);
    o4.y = bfbits((v[u].y - m) * r * w4.y + b4.y);
    o4.z = bfbits((v[u].z - m) * r * w4.z + b4.z);
    o4.w = bfbits((v[u].w - m) * r * w4.w + b4.w);
    ob[l + 64 * u] = o4;
  }
}

// ---------------------------------------------------------------------------
// K9/K10: transpose f32 [R][Cc] -> bf16 [Cc][R]
// ---------------------------------------------------------------------------
__global__ __launch_bounds__(256) void transpose_cast(const float* __restrict__ src,
                                                      hb* __restrict__ dst,
                                                      int R, int Cc) {
  __shared__ float tile[32 * 33];
  const int c0 = blockIdx.x * 32, r0 = blockIdx.y * 32;
  const int tid = threadIdx.x;
#pragma unroll
  for (int u = 0; u < 4; u++) {
    const int idx = tid + u * 256;
    const int r = idx >> 5, c = idx & 31;
    tile[r * 33 + c] = src[(size_t)(r0 + r) * Cc + c0 + c];
  }
  __syncthreads();
#pragma unroll
  for (int u = 0; u < 4; u++) {
    const int idx = tid + u * 256;
    const int c = idx >> 5, r = idx & 31;
    dst[(size_t)(c0 + c) * R + r0 + r] = __float2bfloat16(tile[r * 33 + c]);
  }
}

// ---------------------------------------------------------------------------
// K11/K12: bf16 MFMA GEMM, 128x128 tile, BK=64, 4 waves, 4 blocks/CU —
// the R6-proven version (single-buffer 32KB; dbuf at 64KB measured -35%).
// Conflict-free LDS via both-sides XOR involution swizzle; XCD-aware
// bijective blockIdx swizzle; fast sigmoid-GELU.
// ---------------------------------------------------------------------------
template <int EPI, int NG, int KG>
__global__ __launch_bounds__(256, 4) void gemm_k(const unsigned short* __restrict__ A,
                                                 const unsigned short* __restrict__ Bm,
                                                 const float* __restrict__ bias,
                                                 float* __restrict__ outf,
                                                 hb* __restrict__ outh) {
  __shared__ __align__(16) unsigned short As[128 * 64];
  __shared__ __align__(16) unsigned short Bs[128 * 64];
  constexpr int GN = NG / 128;
  const int nwg = (BT_ / 128) * GN;
  const int bid = blockIdx.x;
  const int wg = (bid & 7) * (nwg >> 3) + (bid >> 3);   // bijective XCD swizzle
  const int m0 = (wg / GN) * 128, n0 = (wg % GN) * 128;
  const int tid = threadIdx.x;
  const int r = tid >> 3, sl = tid & 7;
  const int l = tid & 63, wv = tid >> 6;
  const int wm = wv >> 1, wn = wv & 1;
  const int lr = l & 15, lq = l >> 4;

  f32x4 acc[4][4];
#pragma unroll
  for (int i = 0; i < 4; i++)
#pragma unroll
    for (int j = 0; j < 4; j++) acc[i][j] = f32x4{0.f, 0.f, 0.f, 0.f};

  for (int k0 = 0; k0 < KG; k0 += 64) {
#pragma unroll
    for (int ch = 0; ch < 4; ch++) {
      const int row = ch * 32 + r;
      const int slot = sl ^ (row & 7);                  // inverse-swizzled source
      gload16(A + (size_t)(m0 + row) * KG + k0 + slot * 8, &As[ch * 2048 + tid * 8]);
      gload16(Bm + (size_t)(n0 + row) * KG + k0 + slot * 8, &Bs[ch * 2048 + tid * 8]);
    }
    __syncthreads();
#pragma unroll
    for (int ks = 0; ks < 2; ks++) {
      bf16x8 av[4], bv[4];
#pragma unroll
      for (int i = 0; i < 4; i++) {
        const int row = wm * 64 + i * 16 + lr;
        av[i] = *reinterpret_cast<const bf16x8*>(As + row * 64 + (((ks * 4 + lq) ^ (row & 7)) * 8));
      }
#pragma unroll
      for (int j = 0; j < 4; j++) {
        const int row = wn * 64 + j * 16 + lr;
        bv[j] = *reinterpret_cast<const bf16x8*>(Bs + row * 64 + (((ks * 4 + lq) ^ (row & 7)) * 8));
      }
#pragma unroll
      for (int i = 0; i < 4; i++)
#pragma unroll
        for (int j = 0; j < 4; j++)
          acc[i][j] = __builtin_amdgcn_mfma_f32_16x16x32_bf16(av[i], bv[j], acc[i][j], 0, 0, 0);
    }
    __syncthreads();
  }

#pragma unroll
  for (int i = 0; i < 4; i++) {
#pragma unroll
    for (int j = 0; j < 4; j++) {
      const int n = n0 + wn * 64 + j * 16 + lr;
      const float bn = bias[n];
#pragma unroll
      for (int rr = 0; rr < 4; rr++) {
        const int m = m0 + wm * 64 + i * 16 + lq * 4 + rr;
        const float v = acc[i][j][rr] + bn;
        if constexpr (EPI == 0) {
          const float u = 1.5957691216f * fmaf(0.044715f * v, v * v, v);
          const float ge = v / (1.0f + __expf(-u));
          outh[(size_t)m * NG + n] = __float2bfloat16(ge);
        } else {
          outf[(size_t)m * NG + n] += v;
        }
      }
    }
  }
}

// ---------------------------------------------------------------------------
extern "C" void kernel_launch(void* const* d_in, const int* in_sizes, int n_in,
                              void* d_out, int out_size, void* d_ws, size_t ws_size,
                              hipStream_t stream) {
  (void)in_sizes; (void)n_in; (void)out_size; (void)ws_size;
  const float* x    = (const float*)d_in[0];
  const float* kern = (const float*)d_in[1];
  const float* gain = (const float*)d_in[2];
  const float* gfl  = (const float*)d_in[3];
  const float* gcw  = (const float*)d_in[4];
  const float* gcb  = (const float*)d_in[5];
  const float* lnw  = (const float*)d_in[6];
  const float* lnb  = (const float*)d_in[7];
  const float* flnw = (const float*)d_in[8];
  const float* flnb = (const float*)d_in[9];
  const float* w1   = (const float*)d_in[10];
  const float* b1   = (const float*)d_in[11];
  const float* w2   = (const float*)d_in[12];
  const float* b2   = (const float*)d_in[13];
  const int*   cut  = (const int*)d_in[14];
  float* out = (float*)d_out;

  char* ws = (char*)d_ws;
  size_t off = 0;
  auto alloc = [&](size_t bytes) -> void* {
    void* p = ws + off;
    off += (bytes + 255) & ~(size_t)255;
    return p;
  };
  unsigned short* xtb = (unsigned short*)alloc((size_t)B_ * C_ * T_ * 2);  // 32MB bf16
  hb*    ffin   = (hb*)alloc((size_t)BT_ * C_ * 2);          // 32MB
  hb*    hbuf   = (hb*)alloc((size_t)BT_ * H_ * 2);          // 64MB
  hb*    w1t    = (hb*)alloc((size_t)H_ * C_ * 2);           // 4MB
  hb*    w2t    = (hb*)alloc((size_t)C_ * H_ * 2);           // 4MB
  float* keff   = (float*)alloc((size_t)FB * 2 * 4);
  float* mu     = (float*)alloc((size_t)BT_ * 4);
  float* rs     = (float*)alloc((size_t)BT_ * 4);
  float* parts  = (float*)alloc((size_t)B_ * C_ * (T_ / 32) * 4);  // 2MB
  float* pooled = (float*)alloc((size_t)B_ * C_ * 4);
  float* scale  = (float*)alloc((size_t)B_ * C_ * 4);
  float2* tw    = (float2*)alloc((size_t)TW_TOTAL * 8);      // 48KB twiddles

  build_tw<<<(TW_TOTAL + 255) / 256, 256, 0, stream>>>(tw);
  build_keff<<<FB, 256, 0, stream>>>(kern, gfl, cut, keff);
  ln_stats<<<BT_ / 4, 256, 0, stream>>>(x, mu, rs);
  ln_apply_transpose<<<dim3(T_ / 32, C_ / 128, B_), 256, 0, stream>>>(x, mu, rs, lnw, lnb, xtb, parts);
  pool_finish<<<B_ * C_ / 4, 256, 0, stream>>>(parts, pooled);
  ctx_gate<<<dim3(C_ / 256, B_), 256, 0, stream>>>(pooled, gcw, gcb, gain, scale);
  fftconv<<<B_ * C_, 256, 0, stream>>>(xtb, keff, scale, tw);
  add_residual_transpose<<<dim3(T_ / 128, C_ / 32, B_), 256, 0, stream>>>(x, xtb, out);
  ln2_apply<<<BT_ / 4, 256, 0, stream>>>(out, flnw, flnb, ffin);
  transpose_cast<<<dim3(H_ / 32, C_ / 32), 256, 0, stream>>>(w1, w1t, C_, H_);
  transpose_cast<<<dim3(C_ / 32, H_ / 32), 256, 0, stream>>>(w2, w2t, H_, C_);
  gemm_k<0, H_, C_><<<(BT_ / 128) * (H_ / 128), 256, 0, stream>>>(
      (const unsigned short*)ffin, (const unsigned short*)w1t, b1, nullptr, hbuf);
  gemm_k<1, C_, H_><<<(BT_ / 128) * (C_ / 128), 256, 0, stream>>>(
      (const unsigned short*)hbuf, (const unsigned short*)w2t, b2, out, nullptr);
}

// Round 9
// 306.377 us; speedup vs baseline: 1.3548x; 1.2068x over previous
//
#include <hip/hip_runtime.h>
#include <hip/hip_bf16.h>
#include <hip/hip_fp8.h>
#include <cstdint>
#include <cstddef>

#define DEV static __device__ __forceinline__

typedef __hip_bfloat16 hb;
typedef float f32x4 __attribute__((ext_vector_type(4)));
typedef __attribute__((address_space(1))) unsigned int as1_u32;
typedef __attribute__((address_space(3))) unsigned int as3_u32;

constexpr int B_ = 4, T_ = 4096, C_ = 1024, NFFT = 8192, FB = 4097, H_ = 2048;
constexpr int BT_ = B_ * T_;
constexpr float EPS_ = 1e-5f;
constexpr int TRANS_ = 16;
// twiddle table: [0,240) stage L=16; [240,4080) stage L=256; [4080,6128) untangle.
constexpr int TW_S1 = 0;
constexpr int TW_S2 = 240;
constexpr int TW_UNT = 4080;
constexpr int TW_TOTAL = 6128;
constexpr float WSCALE = 64.0f;          // fp8 weight pre-scale (w sigma=0.01 -> normal range)
constexpr float INV_WS = 1.0f / 64.0f;

DEV void gload16(const void* gsrc, void* ldst) {
  __builtin_amdgcn_global_load_lds((as1_u32*)gsrc, (as3_u32*)ldst, 16, 0, 0);
}

DEV unsigned short bfbits(float f) {
  hb h = __float2bfloat16(f);
  return __builtin_bit_cast(unsigned short, h);
}
DEV float bf2f(unsigned short u) {
  unsigned int x = ((unsigned int)u) << 16;
  return __builtin_bit_cast(float, x);
}
DEV uint8_t f2e4m3(float f) {
  __hip_fp8_e4m3 q(f);                   // OCP e4m3fn, RNE+sat (gfx950 default)
  return (uint8_t)q.__x;
}

// ---------------------------------------------------------------------------
// K0: twiddle tables (shared by all fftconv blocks; L2-resident).
// ---------------------------------------------------------------------------
__global__ __launch_bounds__(256) void build_tw(float2* __restrict__ tw) {
  const int i = blockIdx.x * 256 + threadIdx.x;
  if (i < 240) {                        // stage L=16: W_256^{pq}
    const int pos = i / 15, q = i % 15 + 1;
    float sn, cs;
    sincospif((float)(pos * q) * (1.0f / 128.0f), &sn, &cs);
    tw[i] = make_float2(cs, sn);
  } else if (i < 4080) {                // stage L=256: W_4096^{pq}
    const int j = i - 240;
    const int pos = j / 15, q = j % 15 + 1;
    float sn, cs;
    sincospif((float)(pos * q) * (1.0f / 2048.0f), &sn, &cs);
    tw[i] = make_float2(cs, sn);
  } else if (i < TW_TOTAL) {            // untangle: e^{-i pi k/4096}
    const int k = i - TW_UNT;
    float sn, cs;
    sincospif((float)k * (1.0f / 4096.0f), &sn, &cs);
    tw[i] = make_float2(cs, sn);
  }
}

// ---------------------------------------------------------------------------
// K1: keff[f] = rfft(kernel,8192)[f] * sigmoid(logits[f]) * mask(f, cutoff)
// ---------------------------------------------------------------------------
__global__ __launch_bounds__(256) void build_keff(const float* __restrict__ kern,
                                                  const float* __restrict__ logits,
                                                  const int* __restrict__ cutp,
                                                  float* __restrict__ keff) {
  const int f = blockIdx.x;      // 0..4096
  const int tid = threadIdx.x;
  float sr = 0.f, si = 0.f;
#pragma unroll
  for (int u = 0; u < 4; u++) {
    const int k = tid + u * 256;
    const float kv = kern[k];
    const int m = (f * k) & (NFFT - 1);      // exact phase mod 8192
    float sn, cs;
    sincospif((float)m * (1.0f / 4096.0f), &sn, &cs);  // e^{-2pi i m/8192}
    sr = fmaf(kv, cs, sr);
    si = fmaf(kv, -sn, si);
  }
#pragma unroll
  for (int o = 32; o > 0; o >>= 1) { sr += __shfl_xor(sr, o); si += __shfl_xor(si, o); }
  __shared__ float redr[4], redi[4];
  if ((tid & 63) == 0) { redr[tid >> 6] = sr; redi[tid >> 6] = si; }
  __syncthreads();
  if (tid == 0) {
    float kr = redr[0] + redr[1] + redr[2] + redr[3];
    float ki = redi[0] + redi[1] + redi[2] + redi[3];
    const float g = 1.0f / (1.0f + expf(-logits[f]));
    int cc = *cutp; if (cc > FB) cc = FB;
    float msk = 1.0f;
    if (cc < FB) {                           // mask active (None-case otherwise)
      int tr = TRANS_ < cc ? TRANS_ : cc;
      if (f >= cc) msk = 0.0f;
      else if (f >= cc - tr) {
        int i = f - (cc - tr);
        int den = (tr > 1) ? (tr - 1) : 1;
        msk = 0.5f * (1.0f + cospif((float)i / (float)den));
      }
    }
    const float gm = g * msk;
    keff[2 * f] = kr * gm;
    keff[2 * f + 1] = ki * gm;
  }
}

// ---------------------------------------------------------------------------
// K2: per-row LayerNorm stats (mean, rstd) over C. One wave per row.
// ---------------------------------------------------------------------------
__global__ __launch_bounds__(256) void ln_stats(const float* __restrict__ x,
                                                float* __restrict__ mu,
                                                float* __restrict__ rs) {
  const int row = blockIdx.x * 4 + (threadIdx.x >> 6);
  const int l = threadIdx.x & 63;
  const float4* p = (const float4*)(x + (size_t)row * C_);
  float s = 0.f, sq = 0.f;
#pragma unroll
  for (int u = 0; u < 4; u++) {
    float4 v = p[l + 64 * u];
    s += v.x + v.y + v.z + v.w;
    sq += v.x * v.x + v.y * v.y + v.z * v.z + v.w * v.w;
  }
#pragma unroll
  for (int o = 32; o > 0; o >>= 1) { s += __shfl_xor(s, o); sq += __shfl_xor(sq, o); }
  if (l == 0) {
    float m = s * (1.0f / C_);
    float var = sq * (1.0f / C_) - m * m;
    mu[row] = m;
    rs[row] = rsqrtf(var + EPS_);
  }
}

// ---------------------------------------------------------------------------
// K3: apply LN, transpose [B,T,C] -> bf16 [B,C,T], emit per-tile column sums
// (pooled partials from the f32 values, so g_ctx precision is unchanged).
// ---------------------------------------------------------------------------
__global__ __launch_bounds__(256) void ln_apply_transpose(const float* __restrict__ x,
                                                          const float* __restrict__ mu,
                                                          const float* __restrict__ rs,
                                                          const float* __restrict__ lw,
                                                          const float* __restrict__ lb,
                                                          unsigned short* __restrict__ xtb,
                                                          float* __restrict__ partials) {
  __shared__ float tile[32 * 129];
  const int t0 = blockIdx.x * 32;
  const int c0 = blockIdx.y * 128;
  const int b = blockIdx.z;
  const int tid = threadIdx.x;
#pragma unroll
  for (int u = 0; u < 16; u++) {
    const int idx = tid + u * 256;
    const int row = idx >> 7, col = idx & 127;
    const int t = t0 + row;
    const float v = x[((size_t)(b * T_ + t)) * C_ + c0 + col];
    tile[row * 129 + col] = (v - mu[b * T_ + t]) * rs[b * T_ + t] * lw[c0 + col] + lb[c0 + col];
  }
  __syncthreads();
#pragma unroll
  for (int u = 0; u < 16; u++) {
    const int idx = tid + u * 256;
    const int cc = idx >> 5, tt = idx & 31;
    xtb[((size_t)(b * C_ + c0 + cc)) * T_ + t0 + tt] = bfbits(tile[tt * 129 + cc]);
  }
  if (tid < 128) {
    float s = 0.f;
#pragma unroll
    for (int tt = 0; tt < 32; tt++) s += tile[tt * 129 + tid];
    partials[((size_t)(b * C_ + c0 + tid)) * (T_ / 32) + blockIdx.x] = s;
  }
}

// ---------------------------------------------------------------------------
// K4: pooled[b,c] = sum of 128 tile partials. One wave per (b,c).
// ---------------------------------------------------------------------------
__global__ __launch_bounds__(256) void pool_finish(const float* __restrict__ partials,
                                                   float* __restrict__ pooled) {
  const int bc = blockIdx.x * 4 + (threadIdx.x >> 6);
  const int l = threadIdx.x & 63;
  const float2 v = ((const float2*)(partials + (size_t)bc * 128))[l];
  float s = v.x + v.y;
#pragma unroll
  for (int o = 32; o > 0; o >>= 1) s += __shfl_xor(s, o);
  if (l == 0) pooled[bc] = s;
}

// ---------------------------------------------------------------------------
// K5: scale[b,c] = gain[c] * sigmoid((pooled/T) @ Wctx + bctx)[b,c]
// ---------------------------------------------------------------------------
__global__ __launch_bounds__(256) void ctx_gate(const float* __restrict__ pooled,
                                                const float* __restrict__ W,
                                                const float* __restrict__ cb,
                                                const float* __restrict__ gain,
                                                float* __restrict__ scale) {
  const int b = blockIdx.y;
  const int c = blockIdx.x * 256 + threadIdx.x;
  __shared__ float pm[C_];
#pragma unroll
  for (int u = 0; u < 4; u++)
    pm[threadIdx.x + 256 * u] = pooled[b * C_ + threadIdx.x + 256 * u] * (1.0f / T_);
  __syncthreads();
  float a[8] = {0.f, 0.f, 0.f, 0.f, 0.f, 0.f, 0.f, 0.f};
  for (int k0 = 0; k0 < C_; k0 += 8) {
#pragma unroll
    for (int q = 0; q < 8; q++)
      a[q] = fmaf(pm[k0 + q], W[(size_t)(k0 + q) * C_ + c], a[q]);
  }
  const float z = a[0] + a[1] + a[2] + a[3] + a[4] + a[5] + a[6] + a[7] + cb[c];
  scale[b * C_ + c] = gain[c] * (1.0f / (1.0f + expf(-z)));
}

// ---------------------------------------------------------------------------
// K6: per-(b,c) column conv via radix-16 FFT (4096 = 16^3, 3 LDS stages).
// bf16 global I/O; f32 LDS/compute. (Radix-16 structure proven in R6.)
// ---------------------------------------------------------------------------
DEV int fft_addr(int i) { return i + (i >> 5) + (i >> 10); }   // injective (monotone)
DEV int rev16_3(int n) { return ((n & 15) << 8) | (n & 240) | (n >> 8); }  // involution

DEV void r4ip(float (&xr)[16], float (&xi)[16], const int s0, const int s1,
              const int s2, const int s3, const float SGN) {
  const float a0r = xr[s0] + xr[s2], a0i = xi[s0] + xi[s2];
  const float d0r = xr[s0] - xr[s2], d0i = xi[s0] - xi[s2];
  const float a1r = xr[s1] + xr[s3], a1i = xi[s1] + xi[s3];
  const float d1r = xr[s1] - xr[s3], d1i = xi[s1] - xi[s3];
  xr[s0] = a0r + a1r; xi[s0] = a0i + a1i;
  xr[s2] = a0r - a1r; xi[s2] = a0i - a1i;
  xr[s1] = d0r - SGN * d1i; xi[s1] = d0i + SGN * d1r;
  xr[s3] = d0r + SGN * d1i; xi[s3] = d0i - SGN * d1r;
}

// 16-pt DFT in registers. Output X[k] at slot 4*(k&3)+(k>>2).
// HALF: inputs q>=8 implicitly zero (forward stage 0 with zero-padding).
template <int INV, bool HALF>
DEV void dft16(float (&xr)[16], float (&xi)[16]) {
  constexpr float SGN = INV ? 1.0f : -1.0f;
  constexpr float C1 = 0.9238795325112867f, S1 = 0.3826834323650898f;
  constexpr float R2 = 0.7071067811865476f;
#pragma unroll
  for (int a = 0; a < 4; a++) {
    if constexpr (HALF) {
      const float ar = xr[a], ai = xi[a], br = xr[a + 4], bi = xi[a + 4];
      xr[a] = ar + br;             xi[a] = ai + bi;
      xr[a + 4] = ar - SGN * bi;   xi[a + 4] = ai + SGN * br;
      xr[a + 8] = ar - br;         xi[a + 8] = ai - bi;
      xr[a + 12] = ar + SGN * bi;  xi[a + 12] = ai - SGN * br;
    } else {
      r4ip(xr, xi, a, a + 4, a + 8, a + 12, SGN);
    }
  }
  auto tm = [&](int s, float wr, float wi) {
    const float t = xr[s] * wr - xi[s] * wi;
    xi[s] = xr[s] * wi + xi[s] * wr;
    xr[s] = t;
  };
  tm(5, C1, SGN * S1);
  tm(6, R2, SGN * R2);
  tm(7, S1, SGN * C1);
  tm(9, R2, SGN * R2);
  { const float t = -SGN * xi[10]; xi[10] = SGN * xr[10]; xr[10] = t; }
  tm(11, -R2, SGN * R2);
  tm(13, S1, SGN * C1);
  tm(14, -R2, SGN * R2);
  tm(15, -C1, -SGN * S1);
#pragma unroll
  for (int m = 0; m < 4; m++)
    r4ip(xr, xi, 4 * m + 0, 4 * m + 1, 4 * m + 2, 4 * m + 3, SGN);
}

template <int INV, int L, bool HALF>
DEV void fft_stage(float* sre, float* sim, const int g, const float2* __restrict__ twp) {
  constexpr float SGN = INV ? 1.0f : -1.0f;
  int base, pos;
  if constexpr (L == 1) { base = g << 4; pos = 0; }
  else if constexpr (L == 16) { base = ((g >> 4) << 8) | (g & 15); pos = g & 15; }
  else { base = g; pos = g; }
  float xr[16], xi[16];
#pragma unroll
  for (int q = 0; q < (HALF ? 8 : 16); q++) {
    const int idx = fft_addr(base + q * L);
    xr[q] = sre[idx]; xi[q] = sim[idx];
  }
  if constexpr (L > 1) {
    const float2* tp = twp + pos * 15;
#pragma unroll
    for (int q = 1; q < 16; q++) {
      const float2 w = tp[q - 1];
      const float wr = w.x, wi = SGN * w.y;
      const float t = xr[q] * wr - xi[q] * wi;
      xi[q] = xr[q] * wi + xi[q] * wr;
      xr[q] = t;
    }
  }
  dft16<INV, HALF>(xr, xi);
#pragma unroll
  for (int q = 0; q < 16; q++) {
    const int s = ((q & 3) << 2) | (q >> 2);
    const int idx = fft_addr(base + q * L);
    sre[idx] = xr[s]; sim[idx] = xi[s];
  }
}

__global__ __launch_bounds__(256) void fftconv(unsigned short* __restrict__ xtb,
                                               const float* __restrict__ keff,
                                               const float* __restrict__ scale,
                                               const float2* __restrict__ tw) {
  __shared__ float sre[4226];
  __shared__ float sim[4226];
  const int bc = blockIdx.x;
  const int tid = threadIdx.x;
  unsigned short* col = xtb + (size_t)bc * T_;
  const ushort2* c2 = (const ushort2*)col;
  const float2* k2 = (const float2*)keff;
  const float2* twu = tw + TW_UNT;

  // packed load: z[n] = x[2n] + i x[2n+1] (n<2048); n >= 2048 implicit zero.
#pragma unroll
  for (int u = 0; u < 8; u++) {
    const int n = tid + u * 256;
    const ushort2 v = c2[n];
    const int idx = fft_addr(rev16_3(n));
    sre[idx] = bf2f(v.x); sim[idx] = bf2f(v.y);
  }
  __syncthreads();
  fft_stage<0, 1, true>(sre, sim, tid, tw);
  __syncthreads();
  fft_stage<0, 16, false>(sre, sim, tid, tw + TW_S1);
  __syncthreads();
  fft_stage<0, 256, false>(sre, sim, tid, tw + TW_S2);
  __syncthreads();

  const float s = scale[bc] * (1.0f / 4096.0f);   // fold 1/N of inverse FFT
  float ozr[8], ozi[8], omr[8], omi[8];
#pragma unroll
  for (int u = 0; u < 8; u++) {
    const int k = tid + u * 256;
    if (k == 0) {
      const float z0r = sre[fft_addr(0)], z0i = sim[fft_addr(0)];
      const float zhr = sre[fft_addr(2048)], zhi = sim[fft_addr(2048)];
      const float X0 = z0r + z0i, XN = z0r - z0i;           // X[0], X[4096] (real)
      const float Y0 = X0 * keff[0] * s;
      const float YN = XN * keff[2 * 4096] * s;
      ozr[u] = 0.5f * (Y0 + YN); ozi[u] = 0.5f * (Y0 - YN); // Z'[0]
      const float gr = keff[2 * 2048] * s, gi = keff[2 * 2048 + 1] * s;
      const float Yr = zhr * gr + zhi * gi;                 // Y[2048] = conj(Z[2048])*G
      const float Yi = zhr * gi - zhi * gr;
      omr[u] = Yr; omi[u] = -Yi;                            // Z'[2048] = conj(Y)
    } else {
      const int m = 4096 - k;
      const float zkr = sre[fft_addr(k)], zki = sim[fft_addr(k)];
      const float zmr = sre[fft_addr(m)], zmi = sim[fft_addr(m)];
      const float Ar = 0.5f * (zkr + zmr), Ai = 0.5f * (zki - zmi);
      const float Br = 0.5f * (zki + zmi), Bi = 0.5f * (zmr - zkr);
      const float2 wc = twu[k];                             // e^{-i pi k/4096}
      const float cw = wc.x, sw = wc.y;
      const float Tr = Br * cw + Bi * sw, Ti = Bi * cw - Br * sw;
      const float X1r = Ar + Tr, X1i = Ai + Ti;             // X[k]
      const float X2r = Ar - Tr, X2i = Ti - Ai;             // X[N-k] = conj(A-T)
      const float2 g1 = k2[k], g2 = k2[m];
      const float g1r = g1.x * s, g1i = g1.y * s;
      const float g2r = g2.x * s, g2i = g2.y * s;
      const float Y1r = X1r * g1r - X1i * g1i, Y1i = X1r * g1i + X1i * g1r;
      const float Y2r = X2r * g2r - X2i * g2i, Y2i = X2r * g2i + X2i * g2r;
      const float A1r = 0.5f * (Y1r + Y2r), A1i = 0.5f * (Y1i - Y2i);
      const float Dr = 0.5f * (Y1r - Y2r), Di = 0.5f * (Y1i + Y2i);
      const float B1r = Dr * cw - Di * sw, B1i = Dr * sw + Di * cw;  // e^{+i pi k/N} * D
      ozr[u] = A1r - B1i; ozi[u] = A1i + B1r;   // Z'[k]   = A1 + i B1
      omr[u] = A1r + B1i; omi[u] = B1r - A1i;   // Z'[N-k] = conj(A1) + i conj(B1)
    }
  }
  __syncthreads();
#pragma unroll
  for (int u = 0; u < 8; u++) {
    const int k = tid + u * 256;
    const int m = (k == 0) ? 2048 : 4096 - k;
    const int rk = fft_addr(rev16_3(k)), rm = fft_addr(rev16_3(m));
    sre[rk] = ozr[u]; sim[rk] = ozi[u];
    sre[rm] = omr[u]; sim[rm] = omi[u];
  }
  __syncthreads();
  fft_stage<1, 1, false>(sre, sim, tid, tw);
  __syncthreads();
  fft_stage<1, 16, false>(sre, sim, tid, tw + TW_S1);
  __syncthreads();
  fft_stage<1, 256, false>(sre, sim, tid, tw + TW_S2);
  __syncthreads();

  ushort2* o2 = (ushort2*)col;   // y[2n]=Re z'[n], y[2n+1]=Im z'[n]; keep t<4096
#pragma unroll
  for (int u = 0; u < 8; u++) {
    const int n = tid + u * 256;
    o2[n] = make_ushort2(bfbits(sre[fft_addr(n)]), bfbits(sim[fft_addr(n)]));
  }
}

// ---------------------------------------------------------------------------
// K7: out[b,t,c] = x[b,t,c] + y_t[b,c,t]  (bf16 yt, transpose back + residual)
// ---------------------------------------------------------------------------
__global__ __launch_bounds__(256) void add_residual_transpose(const float* __restrict__ x,
                                                              const unsigned short* __restrict__ ytb,
                                                              float* __restrict__ out) {
  __shared__ float tile[32 * 129];
  const int t0 = blockIdx.x * 128;
  const int c0 = blockIdx.y * 32;
  const int b = blockIdx.z;
  const int tid = threadIdx.x;
#pragma unroll
  for (int u = 0; u < 4; u++) {
    const int idx4 = tid + u * 256;
    const int cr = idx4 >> 5, tq = idx4 & 31;
    const ushort4 v = *(const ushort4*)(ytb + ((size_t)(b * C_ + c0 + cr)) * T_ + t0 + tq * 4);
    tile[cr * 129 + tq * 4 + 0] = bf2f(v.x);
    tile[cr * 129 + tq * 4 + 1] = bf2f(v.y);
    tile[cr * 129 + tq * 4 + 2] = bf2f(v.z);
    tile[cr * 129 + tq * 4 + 3] = bf2f(v.w);
  }
  __syncthreads();
#pragma unroll
  for (int u = 0; u < 16; u++) {
    const int idx = tid + u * 256;
    const int tr = idx >> 5, cc = idx & 31;
    const size_t o = ((size_t)(b * T_ + t0 + tr)) * C_ + c0 + cc;
    out[o] = x[o] + tile[cc * 129 + tr];
  }
}

// ---------------------------------------------------------------------------
// K8: fused LN over x2 rows -> fp8 ff_in. One wave per row, values in regs.
// ---------------------------------------------------------------------------
__global__ __launch_bounds__(256) void ln2_apply(const float* __restrict__ x2,
                                                 const float* __restrict__ lw,
                                                 const float* __restrict__ lb,
                                                 uint8_t* __restrict__ outq) {
  const int row = blockIdx.x * 4 + (threadIdx.x >> 6);
  const int l = threadIdx.x & 63;
  const float4* p = (const float4*)(x2 + (size_t)row * C_);
  float4 v[4];
  float s = 0.f, sq = 0.f;
#pragma unroll
  for (int u = 0; u < 4; u++) {
    v[u] = p[l + 64 * u];
    s += v[u].x + v[u].y + v[u].z + v[u].w;
    sq += v[u].x * v[u].x + v[u].y * v[u].y + v[u].z * v[u].z + v[u].w * v[u].w;
  }
#pragma unroll
  for (int o = 32; o > 0; o >>= 1) { s += __shfl_xor(s, o); sq += __shfl_xor(sq, o); }
  const float m = s * (1.0f / C_);
  const float r = rsqrtf(sq * (1.0f / C_) - m * m + EPS_);
  uchar4* ob = (uchar4*)(outq + (size_t)row * C_);
  const float4* wp = (const float4*)lw;
  const float4* bp = (const float4*)lb;
#pragma unroll
  for (int u = 0; u < 4; u++) {
    const float4 w4 = wp[l + 64 * u], b4 = bp[l + 64 * u];
    uchar4 o4;
    o4.x = f2e4m3((v[u].x - m) * r * w4.x + b4.x);
    o4.y = f2e4m3((v[u].y - m) * r * w4.y + b4.y);
    o4.z = f2e4m3((v[u].z - m) * r * w4.z + b4.z);
    o4.w = f2e4m3((v[u].w - m) * r * w4.w + b4.w);
    ob[l + 64 * u] = o4;
  }
}

// ---------------------------------------------------------------------------
// K9/K10: transpose f32 [R][Cc] -> fp8 [Cc][R], pre-scaled by WSCALE.
// ---------------------------------------------------------------------------
__global__ __launch_bounds__(256) void transpose_cast(const float* __restrict__ src,
                                                      uint8_t* __restrict__ dst,
                                                      int R, int Cc) {
  __shared__ float tile[32 * 33];
  const int c0 = blockIdx.x * 32, r0 = blockIdx.y * 32;
  const int tid = threadIdx.x;
#pragma unroll
  for (int u = 0; u < 4; u++) {
    const int idx = tid + u * 256;
    const int r = idx >> 5, c = idx & 31;
    tile[r * 33 + c] = src[(size_t)(r0 + r) * Cc + c0 + c];
  }
  __syncthreads();
#pragma unroll
  for (int u = 0; u < 4; u++) {
    const int idx = tid + u * 256;
    const int c = idx >> 5, r = idx & 31;
    dst[(size_t)(c0 + c) * R + r0 + r] = f2e4m3(tile[r * 33 + c] * WSCALE);
  }
}

// ---------------------------------------------------------------------------
// K11/K12: fp8-e4m3 MFMA GEMM, 128x128 tile, BK=128 (128B rows), 4 waves,
// 4 blocks/CU (32KB LDS, same as R6/R8 structure). Both-sides 16B-slot XOR
// involution swizzle (slot ^= row&7): wave b64 fragment reads hit the 4-phase
// bank floor. Weights pre-scaled by WSCALE; acc * INV_WS in epilogue.
// A: [M][KG] fp8 row-major. Bm: [NG][KG] fp8 row-major (B^T).
// EPI 0: outq = fp8(gelu(acc/WS+bias)); EPI 1: outf += acc/WS + bias.
// ---------------------------------------------------------------------------
template <int EPI, int NG, int KG>
__global__ __launch_bounds__(256, 4) void gemm_k(const uint8_t* __restrict__ A,
                                                 const uint8_t* __restrict__ Bm,
                                                 const float* __restrict__ bias,
                                                 float* __restrict__ outf,
                                                 uint8_t* __restrict__ outq) {
  __shared__ __align__(16) uint8_t As[128 * 128];
  __shared__ __align__(16) uint8_t Bs[128 * 128];
  constexpr int GN = NG / 128;
  const int nwg = (BT_ / 128) * GN;
  const int bid = blockIdx.x;
  const int wg = (bid & 7) * (nwg >> 3) + (bid >> 3);   // bijective XCD swizzle
  const int m0 = (wg / GN) * 128, n0 = (wg % GN) * 128;
  const int tid = threadIdx.x;
  const int r = tid >> 3, sl = tid & 7;    // 32 rows x 8 slots(16B) per pass
  const int l = tid & 63, wv = tid >> 6;
  const int wm = wv >> 1, wn = wv & 1;
  const int lr = l & 15, lq = l >> 4;

  f32x4 acc[4][4];
#pragma unroll
  for (int i = 0; i < 4; i++)
#pragma unroll
    for (int j = 0; j < 4; j++) acc[i][j] = f32x4{0.f, 0.f, 0.f, 0.f};

  for (int k0 = 0; k0 < KG; k0 += 128) {
#pragma unroll
    for (int ch = 0; ch < 4; ch++) {
      const int row = ch * 32 + r;
      const int slot = sl ^ (row & 7);                  // inverse-swizzled source
      gload16(A + (size_t)(m0 + row) * KG + k0 + slot * 16, &As[ch * 4096 + tid * 16]);
      gload16(Bm + (size_t)(n0 + row) * KG + k0 + slot * 16, &Bs[ch * 4096 + tid * 16]);
    }
    __syncthreads();
#pragma unroll
    for (int kk = 0; kk < 4; kk++) {                    // 4 x K=32 MFMA slices
      const int j8 = kk * 4 + lq;                       // 8B-granule index 0..15
      const int jh = j8 >> 1, jl = (j8 & 1) * 8;
      long av[4], bv[4];
#pragma unroll
      for (int i = 0; i < 4; i++) {
        const int row = wm * 64 + i * 16 + lr;
        av[i] = *reinterpret_cast<const long*>(&As[row * 128 + ((jh ^ (row & 7)) * 16) + jl]);
      }
#pragma unroll
      for (int j = 0; j < 4; j++) {
        const int row = wn * 64 + j * 16 + lr;
        bv[j] = *reinterpret_cast<const long*>(&Bs[row * 128 + ((jh ^ (row & 7)) * 16) + jl]);
      }
#pragma unroll
      for (int i = 0; i < 4; i++)
#pragma unroll
        for (int j = 0; j < 4; j++)
          acc[i][j] = __builtin_amdgcn_mfma_f32_16x16x32_fp8_fp8(av[i], bv[j], acc[i][j], 0, 0, 0);
    }
    __syncthreads();
  }

#pragma unroll
  for (int i = 0; i < 4; i++) {
#pragma unroll
    for (int j = 0; j < 4; j++) {
      const int n = n0 + wn * 64 + j * 16 + lr;
      const float bn = bias[n];
#pragma unroll
      for (int rr = 0; rr < 4; rr++) {
        const int m = m0 + wm * 64 + i * 16 + lq * 4 + rr;
        const float v = fmaf(acc[i][j][rr], INV_WS, bn);
        if constexpr (EPI == 0) {
          const float u = 1.5957691216f * fmaf(0.044715f * v, v * v, v);
          const float ge = v / (1.0f + __expf(-u));
          outq[(size_t)m * NG + n] = f2e4m3(ge);
        } else {
          outf[(size_t)m * NG + n] += v;
        }
      }
    }
  }
}

// ---------------------------------------------------------------------------
extern "C" void kernel_launch(void* const* d_in, const int* in_sizes, int n_in,
                              void* d_out, int out_size, void* d_ws, size_t ws_size,
                              hipStream_t stream) {
  (void)in_sizes; (void)n_in; (void)out_size; (void)ws_size;
  const float* x    = (const float*)d_in[0];
  const float* kern = (const float*)d_in[1];
  const float* gain = (const float*)d_in[2];
  const float* gfl  = (const float*)d_in[3];
  const float* gcw  = (const float*)d_in[4];
  const float* gcb  = (const float*)d_in[5];
  const float* lnw  = (const float*)d_in[6];
  const float* lnb  = (const float*)d_in[7];
  const float* flnw = (const float*)d_in[8];
  const float* flnb = (const float*)d_in[9];
  const float* w1   = (const float*)d_in[10];
  const float* b1   = (const float*)d_in[11];
  const float* w2   = (const float*)d_in[12];
  const float* b2   = (const float*)d_in[13];
  const int*   cut  = (const int*)d_in[14];
  float* out = (float*)d_out;

  char* ws = (char*)d_ws;
  size_t off = 0;
  auto alloc = [&](size_t bytes) -> void* {
    void* p = ws + off;
    off += (bytes + 255) & ~(size_t)255;
    return p;
  };
  unsigned short* xtb = (unsigned short*)alloc((size_t)B_ * C_ * T_ * 2);  // 32MB bf16
  uint8_t* ffin  = (uint8_t*)alloc((size_t)BT_ * C_);        // 16MB fp8
  uint8_t* hbuf  = (uint8_t*)alloc((size_t)BT_ * H_);        // 32MB fp8
  uint8_t* w1t   = (uint8_t*)alloc((size_t)H_ * C_);         // 2MB fp8 (x WSCALE)
  uint8_t* w2t   = (uint8_t*)alloc((size_t)C_ * H_);         // 2MB fp8 (x WSCALE)
  float* keff   = (float*)alloc((size_t)FB * 2 * 4);
  float* mu     = (float*)alloc((size_t)BT_ * 4);
  float* rs     = (float*)alloc((size_t)BT_ * 4);
  float* parts  = (float*)alloc((size_t)B_ * C_ * (T_ / 32) * 4);  // 2MB
  float* pooled = (float*)alloc((size_t)B_ * C_ * 4);
  float* scale  = (float*)alloc((size_t)B_ * C_ * 4);
  float2* tw    = (float2*)alloc((size_t)TW_TOTAL * 8);      // 48KB twiddles

  build_tw<<<(TW_TOTAL + 255) / 256, 256, 0, stream>>>(tw);
  build_keff<<<FB, 256, 0, stream>>>(kern, gfl, cut, keff);
  ln_stats<<<BT_ / 4, 256, 0, stream>>>(x, mu, rs);
  ln_apply_transpose<<<dim3(T_ / 32, C_ / 128, B_), 256, 0, stream>>>(x, mu, rs, lnw, lnb, xtb, parts);
  pool_finish<<<B_ * C_ / 4, 256, 0, stream>>>(parts, pooled);
  ctx_gate<<<dim3(C_ / 256, B_), 256, 0, stream>>>(pooled, gcw, gcb, gain, scale);
  fftconv<<<B_ * C_, 256, 0, stream>>>(xtb, keff, scale, tw);
  add_residual_transpose<<<dim3(T_ / 128, C_ / 32, B_), 256, 0, stream>>>(x, xtb, out);
  ln2_apply<<<BT_ / 4, 256, 0, stream>>>(out, flnw, flnb, ffin);
  transpose_cast<<<dim3(H_ / 32, C_ / 32), 256, 0, stream>>>(w1, w1t, C_, H_);
  transpose_cast<<<dim3(C_ / 32, H_ / 32), 256, 0, stream>>>(w2, w2t, H_, C_);
  gemm_k<0, H_, C_><<<(BT_ / 128) * (H_ / 128), 256, 0, stream>>>(
      ffin, w1t, b1, nullptr, hbuf);
  gemm_k<1, C_, H_><<<(BT_ / 128) * (C_ / 128), 256, 0, stream>>>(
      hbuf, w2t, b2, out, nullptr);
}